// Round 2
// baseline (533.707 us; speedup 1.0000x reference)
//
#include <hip/hip_runtime.h>

// CrossJointAttention fused kernel for MI355X (gfx950) -- Round 4 (= R3 resubmit;
// R3 bench died to an infra container failure, no counters returned).
// B=16384, N=12 joints, D=128, H=4, hd=32. fp32 in/out, bf16 MFMA internally.
//
// Changes vs R2 (which was latency-bound: 31.6% occupancy, VALUBusy 20%,
// MfmaUtil 7.7%, HBM 12.6% -- every pipe idle, waves stalled on phase-1
// global x loads and per-WG fixed overhead):
//  - PERSISTENT workgroups: grid 1024, each WG processes GPW=4 batch-groups.
//    Prologue (vT pad zeros, bias_s, bvec) runs once per WG, not per group.
//  - Cross-group x PREFETCH: next group's 24 global_load_dwordx4 issue at
//    phase-2 start (covered by attention + Wo GEMM), packed to bf16 at
//    phase-2 end, consumed by next round's phase 1 -> phase-1 HBM latency
//    hidden for 3 of 4 rounds.
//  - Phase 1 split into QK pass + V pass to cap live accumulators while the
//    96-VGPR xr prefetch block is alive (budget: 170 VGPR at 3 waves/SIMD).
//  - Output stores deferred past the round barrier (held in regs, stored at
//    next round's top) so the barrier's vmcnt(0) drain never waits on
//    write-acks.
// Everything numerically sensitive (MFMA fragment layouts, exp2 softmax,
// VPAD=20 conflict-free vT, P round-trip, epilogues) is unchanged from R2.

typedef unsigned short u16;
typedef short bf16x8 __attribute__((ext_vector_type(8)));   // 8 bf16 = 4 VGPRs
typedef short bf16x4 __attribute__((ext_vector_type(4)));   // 4 bf16 = 2 VGPRs
typedef float f32x4 __attribute__((ext_vector_type(4)));

#define MFMA(a, b, c) __builtin_amdgcn_mfma_f32_16x16x32_bf16((a), (b), (c), 0, 0, 0)

#define BPW   4            // batches per group
#define ROWS  (BPW * 12)   // 48 joint-rows per group
#define XPAD  136          // row stride (bf16) for q/k/ctx: 272B, 16B-aligned
#define VPAD  20           // vT row stride: 40B -> bank coeff 10 (odd*2), 8B-aligned
#define PPAD  20           // P row stride
#define GPW   4            // groups per (persistent) workgroup

struct SMem {
    u16   qs[ROWS * XPAD];       // q rows [48][128]; ctx overlays per-head
    u16   ks[ROWS * XPAD];       // k rows
    u16   vT[BPW * 128 * VPAD];  // per batch [feat][joint pad 20]; cols 12..19 zeroed once
    u16   P[4 * 16 * PPAD];      // per wave unnormalized exp [n][m pad 20]
    float bias_s[16 * 16];       // adj*scale*log2e; -1e30 for m>=12; 0 for n>=12
    float vis_s[BPW * 16];       // 10*(1-vis)*log2e; 0 for pad  (per-round)
    float bvec[4 * 128];         // bq | bk | bv | bo
    float rls[4 * 16];           // per wave: 1/rowsum for each n
};

__device__ __forceinline__ u16 f2b(float f) {   // fp32 -> bf16 RNE
    unsigned u = __builtin_bit_cast(unsigned, f);
    return (u16)((u + 0x7fffu + ((u >> 16) & 1u)) >> 16);
}

__device__ __forceinline__ void st4(u16* p, float a, float b, float c, float d) {
    ushort4 v; v.x = f2b(a); v.y = f2b(b); v.z = f2b(c); v.w = f2b(d);
    *(ushort4*)p = v;   // ds_write_b64
}

__device__ __forceinline__ bf16x8 pack8(float4 a, float4 b) {
    bf16x8 r;
    r[0] = (short)f2b(a.x); r[1] = (short)f2b(a.y);
    r[2] = (short)f2b(a.z); r[3] = (short)f2b(a.w);
    r[4] = (short)f2b(b.x); r[5] = (short)f2b(b.y);
    r[6] = (short)f2b(b.z); r[7] = (short)f2b(b.w);
    return r;
}

__global__ void prep_w(const float* __restrict__ Wq, const float* __restrict__ Wk,
                       const float* __restrict__ Wv, const float* __restrict__ Wo,
                       u16* __restrict__ wbf) {
    int i = blockIdx.x * 256 + threadIdx.x;     // 0..16383
    wbf[i]         = f2b(Wq[i]);
    wbf[16384 + i] = f2b(Wk[i]);
    wbf[32768 + i] = f2b(Wv[i]);
    wbf[49152 + i] = f2b(Wo[i]);
}

__global__ __launch_bounds__(256, 3) void cja_main(
    const float* __restrict__ x, const float* __restrict__ vis,
    const float* __restrict__ bq, const float* __restrict__ bk,
    const float* __restrict__ bv, const float* __restrict__ bo,
    const float* __restrict__ bias_scale, const float* __restrict__ adj,
    const u16* __restrict__ wbf, float* __restrict__ out)
{
    extern __shared__ char smraw[];
    SMem& sm = *(SMem*)smraw;

    const int tid  = threadIdx.x;
    const int wave = tid >> 6;
    const int lane = tid & 63;
    const int lq   = lane >> 4;      // quadrant 0..3
    const int lm   = lane & 15;      // 0..15
    const int grp0 = blockIdx.x * GPW;

    // ---- cross-round x prefetch state (register-resident, static-indexed) --
    float4 xr[12][2];   // raw fp32 tile fragments (96 VGPRs while live)
    bf16x8 xf[12];      // packed bf16 fragments   (48 VGPRs)

    auto issue_x = [&](int grp) {
        const float* xw = x + (size_t)grp * (BPW * 12 * 128);
        #pragma unroll
        for (int ks2 = 0; ks2 < 4; ks2++)
            #pragma unroll
            for (int nt = 0; nt < 3; nt++) {
                const float* xp = xw + (nt * 16 + lm) * 128 + ks2 * 32 + lq * 8;
                xr[ks2 * 3 + nt][0] = *(const float4*)xp;
                xr[ks2 * 3 + nt][1] = *(const float4*)(xp + 4);
            }
    };
    auto pack_x = [&]() {
        #pragma unroll
        for (int i = 0; i < 12; i++) xf[i] = pack8(xr[i][0], xr[i][1]);
    };

    issue_x(grp0);   // loads for round 0 fly over the prologue

    // ---------------- One-time prologue -------------------------------------
    for (int i = tid; i < BPW * 128; i += 256) {          // zero vT cols 12..19
        unsigned* d = (unsigned*)(sm.vT + i * VPAD + 12); // byte 40i+24: 8B-aligned
        d[0] = 0u; d[1] = 0u; d[2] = 0u; d[3] = 0u;       // scatter never touches these
    }
    const float L2E = 1.4426950408889634f;
    {
        float scale = bias_scale[0] * L2E;
        int n = tid >> 4, m = tid & 15;
        float bval;
        if (m >= 12)     bval = -1e30f;                   // key-pad mask (exp2 -> 0)
        else if (n < 12) bval = adj[n * 12 + m] * scale;
        else             bval = 0.0f;                     // row pad: keep finite
        sm.bias_s[tid] = bval;
        if (tid < 128) {
            sm.bvec[tid]       = bq[tid];
            sm.bvec[128 + tid] = bk[tid];
            sm.bvec[256 + tid] = bv[tid];
            sm.bvec[384 + tid] = bo[tid];
        }
    }
    pack_x();        // one-time exposed latency for round 0
    __syncthreads();

    // ---- round-invariant phase-2/3 addressing ------------------------------
    const int bl  = wave;
    const int nql = (lm < 12) ? lm : 11;                  // clamp: no OOB reads
    const u16* qrowp = sm.qs + (bl * 12 + nql) * XPAD;
    const u16* krowp = sm.ks + (bl * 12 + nql) * XPAD;
    u16*   Pw  = sm.P + wave * (16 * PPAD);
    float* rlw = sm.rls + wave * 16;
    const u16* vTb = sm.vT + bl * (128 * VPAD);
    const int mrow0 = wave * 32 + lm;                     // weight row (feature)
    const int mrow1 = mrow0 + 16;
    float bias_b[4];
    #pragma unroll
    for (int rr = 0; rr < 4; rr++) bias_b[rr] = sm.bias_s[(lq * 4 + rr) * 16 + lm];

    f32x4 oacc[2][3];   // deferred output (bias folded), stored next round

    #pragma unroll 1
    for (int rnd = 0; rnd < GPW; ++rnd) {
        const int grp = grp0 + rnd;
        const int b0  = grp * BPW;

        // ---- deferred store of previous round's output (drains by B1) ------
        if (rnd > 0) {
            const int b0p = b0 - BPW;
            #pragma unroll
            for (int mi = 0; mi < 2; mi++) {
                const int e0 = (wave * 2 + mi) * 16 + lq * 4;
                #pragma unroll
                for (int nt = 0; nt < 3; nt++) {
                    const int n = nt * 16 + lm;
                    *(f32x4*)(out + ((size_t)(b0p * 12 + n) << 7) + e0) = oacc[mi][nt];
                }
            }
        }

        // ---- visibility for this round (wave 0; consumed after B1) ---------
        if (tid < 64) {
            int bb = tid >> 4, mm = tid & 15;
            sm.vis_s[tid] = (mm < 12) ? 10.0f * L2E * (1.0f - vis[(size_t)(b0 + bb) * 12 + mm])
                                      : 0.0f;
        }

        // ---------------- Phase 1: fused Q/K then V GEMMs (x from xf) -------
        {
            // QK pass (keeps live accs at 48 while xf=48 is resident)
            const u16* Wq_b = wbf;
            const u16* Wk_b = wbf + 16384;
            f32x4 accq[2][3], acck[2][3];
            #pragma unroll
            for (int i = 0; i < 2; i++)
                #pragma unroll
                for (int j = 0; j < 3; j++) { accq[i][j] = (f32x4){0,0,0,0}; acck[i][j] = (f32x4){0,0,0,0}; }
            #pragma unroll
            for (int ks2 = 0; ks2 < 4; ks2++) {
                const int koff = ks2 * 32 + lq * 8;
                bf16x8 wq0 = *(const bf16x8*)(Wq_b + mrow0 * 128 + koff);
                bf16x8 wq1 = *(const bf16x8*)(Wq_b + mrow1 * 128 + koff);
                bf16x8 wk0 = *(const bf16x8*)(Wk_b + mrow0 * 128 + koff);
                bf16x8 wk1 = *(const bf16x8*)(Wk_b + mrow1 * 128 + koff);
                #pragma unroll
                for (int nt = 0; nt < 3; nt++) {
                    accq[0][nt] = MFMA(wq0, xf[ks2*3+nt], accq[0][nt]);   // C[e,n] = Wq . x^T
                    accq[1][nt] = MFMA(wq1, xf[ks2*3+nt], accq[1][nt]);
                    acck[0][nt] = MFMA(wk0, xf[ks2*3+nt], acck[0][nt]);
                    acck[1][nt] = MFMA(wk1, xf[ks2*3+nt], acck[1][nt]);
                }
            }
            // epilogue Q/K: transposed store -> q,k row-major [joint-row][feat]
            #pragma unroll
            for (int mi = 0; mi < 2; mi++) {
                const int e0 = (wave * 2 + mi) * 16 + lq * 4;
                float bq0 = sm.bvec[e0], bq1 = sm.bvec[e0+1], bq2 = sm.bvec[e0+2], bq3 = sm.bvec[e0+3];
                float bk0 = sm.bvec[128+e0], bk1 = sm.bvec[128+e0+1], bk2 = sm.bvec[128+e0+2], bk3 = sm.bvec[128+e0+3];
                #pragma unroll
                for (int nt = 0; nt < 3; nt++) {
                    const int n = nt * 16 + lm;                   // joint-row 0..47
                    st4(sm.qs + n * XPAD + e0, accq[mi][nt][0]+bq0, accq[mi][nt][1]+bq1,
                                               accq[mi][nt][2]+bq2, accq[mi][nt][3]+bq3);
                    st4(sm.ks + n * XPAD + e0, acck[mi][nt][0]+bk0, acck[mi][nt][1]+bk1,
                                               acck[mi][nt][2]+bk2, acck[mi][nt][3]+bk3);
                }
            }
            // V pass
            const u16* Wv_b = wbf + 32768;
            f32x4 accv[3][2];
            #pragma unroll
            for (int i = 0; i < 3; i++)
                #pragma unroll
                for (int j = 0; j < 2; j++) accv[i][j] = (f32x4){0,0,0,0};
            #pragma unroll
            for (int ks2 = 0; ks2 < 4; ks2++) {
                const int koff = ks2 * 32 + lq * 8;
                bf16x8 wv0 = *(const bf16x8*)(Wv_b + mrow0 * 128 + koff);
                bf16x8 wv1 = *(const bf16x8*)(Wv_b + mrow1 * 128 + koff);
                #pragma unroll
                for (int nt = 0; nt < 3; nt++) {
                    accv[nt][0] = MFMA(xf[ks2*3+nt], wv0, accv[nt][0]);   // C[n,e] = x . Wv^T
                    accv[nt][1] = MFMA(xf[ks2*3+nt], wv1, accv[nt][1]);
                }
            }
            // epilogue V: scatter -> vT[batch][feat][joint], stride 20 (conflict-free)
            #pragma unroll
            for (int nt2 = 0; nt2 < 2; nt2++) {
                const int e = (wave * 2 + nt2) * 16 + lm;         // feature column
                const float bvv = sm.bvec[256 + e];
                #pragma unroll
                for (int mt = 0; mt < 3; mt++) {
                    #pragma unroll
                    for (int r = 0; r < 4; r++) {
                        int n = mt * 16 + lq * 4 + r;             // joint-row 0..47
                        int bb = n / 12, j = n - bb * 12;
                        sm.vT[bb * (128 * VPAD) + e * VPAD + j] = f2b(accv[mt][nt2][r] + bvv);
                    }
                }
            }
        }
        __syncthreads();   // B1

        // ---------------- Phase 2: attention (wave w owns batch w) ----------
        {
            if (rnd + 1 < GPW) issue_x(grp + 1);          // prefetch flies over P2+P3

            const float vism = sm.vis_s[bl * 16 + lm];
            const float SC2 = 0.2550348606381560f;        // (1/sqrt(32))*log2(e)
            const bf16x8 z8 = {0,0,0,0,0,0,0,0};
            #pragma unroll
            for (int h = 0; h < 4; h++) {
                bf16x8 qa = *(const bf16x8*)(qrowp + h * 32 + lq * 8);
                bf16x8 kb = *(const bf16x8*)(krowp + h * 32 + lq * 8);
                f32x4 sc = MFMA(qa, kb, ((f32x4){0,0,0,0}));      // scores[n,m]
                #pragma unroll
                for (int r = 0; r < 4; r++) {
                    float s2 = sc[r] * SC2 + bias_b[r] - vism;    // base-2 domain
                    float e  = __builtin_amdgcn_exp2f(s2);        // 0 exactly for pads
                    float l  = e;
                    l += __shfl_xor(l, 1, 16);
                    l += __shfl_xor(l, 2, 16);
                    l += __shfl_xor(l, 4, 16);
                    l += __shfl_xor(l, 8, 16);
                    Pw[(lq * 4 + r) * PPAD + lm] = f2b(e);        // unnormalized
                    if (lm == 0) rlw[lq * 4 + r] = __builtin_amdgcn_rcpf(l);
                }
                float rln = rlw[lm];                              // 1/l for col n=lm
                bf16x8 pb = z8;                                   // quads 2,3 = zero (K-ext 16)
                if (lq < 2) {
                    const bf16x4* pp = (const bf16x4*)(Pw + lm * PPAD + lq * 8);
                    pb = __builtin_shufflevector(pp[0], pp[1], 0, 1, 2, 3, 4, 5, 6, 7);
                }
                #pragma unroll
                for (int mt = 0; mt < 2; mt++) {
                    bf16x8 va = z8;
                    if (lq < 2) {
                        const bf16x4* vp = (const bf16x4*)(vTb + (h * 32 + mt * 16 + lm) * VPAD + lq * 8);
                        va = __builtin_shufflevector(vp[0], vp[1], 0, 1, 2, 3, 4, 5, 6, 7);
                    }
                    f32x4 c = MFMA(va, pb, ((f32x4){0,0,0,0}));   // C[e',n]
                    if (lm < 12) {                                 // ctx overlays qs
                        u16* d = sm.qs + (bl * 12 + lm) * XPAD + h * 32 + mt * 16 + lq * 4;
                        st4(d, c[0] * rln, c[1] * rln, c[2] * rln, c[3] * rln);
                    }
                }
            }

            if (rnd + 1 < GPW) pack_x();                  // arrivals covered by P2
        }
        __syncthreads();   // B2

        // ---------------- Phase 3: output projection (no store yet) ---------
        {
            const u16* Wo_b = wbf + 49152;
            f32x4 acc[2][3];
            #pragma unroll
            for (int i = 0; i < 2; i++)
                #pragma unroll
                for (int j = 0; j < 3; j++) acc[i][j] = (f32x4){0,0,0,0};
            #pragma unroll
            for (int ks2 = 0; ks2 < 4; ks2++) {
                const int koff = ks2 * 32 + lq * 8;
                bf16x8 a0 = *(const bf16x8*)(Wo_b + mrow0 * 128 + koff);
                bf16x8 a1 = *(const bf16x8*)(Wo_b + (mrow1) * 128 + koff);
                #pragma unroll
                for (int nt = 0; nt < 3; nt++) {
                    bf16x8 bfr = *(const bf16x8*)(sm.qs + (nt * 16 + lm) * XPAD + koff);
                    acc[0][nt] = MFMA(a0, bfr, acc[0][nt]);
                    acc[1][nt] = MFMA(a1, bfr, acc[1][nt]);
                }
            }
            #pragma unroll
            for (int mi = 0; mi < 2; mi++) {
                const int e0 = (wave * 2 + mi) * 16 + lq * 4;
                float bo0 = sm.bvec[384+e0], bo1 = sm.bvec[384+e0+1],
                      bo2 = sm.bvec[384+e0+2], bo3 = sm.bvec[384+e0+3];
                #pragma unroll
                for (int nt = 0; nt < 3; nt++) {
                    oacc[mi][nt][0] = acc[mi][nt][0] + bo0;
                    oacc[mi][nt][1] = acc[mi][nt][1] + bo1;
                    oacc[mi][nt][2] = acc[mi][nt][2] + bo2;
                    oacc[mi][nt][3] = acc[mi][nt][3] + bo3;
                }
            }
        }
        if (rnd + 1 < GPW) __syncthreads();   // B3: protect qs/ks/vT for next P1
    }

    // ---- final round's deferred store --------------------------------------
    {
        const int b0p = (grp0 + GPW - 1) * BPW;
        #pragma unroll
        for (int mi = 0; mi < 2; mi++) {
            const int e0 = (wave * 2 + mi) * 16 + lq * 4;
            #pragma unroll
            for (int nt = 0; nt < 3; nt++) {
                const int n = nt * 16 + lm;
                *(f32x4*)(out + ((size_t)(b0p * 12 + n) << 7) + e0) = oacc[mi][nt];
            }
        }
    }
}

extern "C" void kernel_launch(void* const* d_in, const int* in_sizes, int n_in,
                              void* d_out, int out_size, void* d_ws, size_t ws_size,
                              hipStream_t stream) {
    const float* x   = (const float*)d_in[0];
    const float* vis = (const float*)d_in[1];
    const float* Wq  = (const float*)d_in[2];
    const float* bq  = (const float*)d_in[3];
    const float* Wk  = (const float*)d_in[4];
    const float* bk  = (const float*)d_in[5];
    const float* Wv  = (const float*)d_in[6];
    const float* bv  = (const float*)d_in[7];
    const float* Wo  = (const float*)d_in[8];
    const float* bo  = (const float*)d_in[9];
    const float* bs  = (const float*)d_in[10];
    const float* adj = (const float*)d_in[11];
    u16* wbf = (u16*)d_ws;   // 4 x 128x128 bf16 = 128KB

    prep_w<<<64, 256, 0, stream>>>(Wq, Wk, Wv, Wo, wbf);
    cja_main<<<16384 / (BPW * GPW), 256, sizeof(SMem), stream>>>(
        x, vis, bq, bk, bv, bo, bs, adj, wbf, (float*)d_out);
}

// Round 3
// 441.022 us; speedup vs baseline: 1.2102x; 1.2102x over previous
//
#include <hip/hip_runtime.h>

// CrossJointAttention fused kernel for MI355X (gfx950) -- Round 5.
// B=16384, N=12 joints, D=128, H=4, hd=32. fp32 in/out, bf16 MFMA internally.
//
// R5 vs R4 post-mortem fixes (R4: 412us, WRITE_SIZE 527MB = xr/xf demoted to
// scratch because old-xf stayed live through phase 2 -> peak ~180 VGPR > 168
// cap; plus grid 1024 over 768 resident slots = +50% tail quantization):
//  - Grid 768 (exactly 3 WG/CU by LDS), GRID-STRIDE over 4096 groups ->
//    5-6 rounds/WG, +12.5% quantization (same as R2's 4096x1 grid).
//  - Prefetch both halves issue at PHASE-2 START (old xf dead there).
//    Stage A: pack at phase-2 end (counted vmcnt, B stays in flight).
//    Stage B: drained by B2's mandatory vmcnt(0), packed (VALU-only) at
//    phase-3 start. Peak pressure xra48+xrb48+phase2~35 = ~131 < 168.
//  - vis loaded per-wave into registers (vis_s LDS field removed).
//  - Kept from R4: one-time prologue, deferred output stores past barrier.
// Numerics (MFMA layouts, exp2 softmax, VPAD=20 vT, P round-trip) unchanged.

typedef unsigned short u16;
typedef short bf16x8 __attribute__((ext_vector_type(8)));   // 8 bf16 = 4 VGPRs
typedef short bf16x4 __attribute__((ext_vector_type(4)));   // 4 bf16 = 2 VGPRs
typedef float f32x4 __attribute__((ext_vector_type(4)));

#define MFMA(a, b, c) __builtin_amdgcn_mfma_f32_16x16x32_bf16((a), (b), (c), 0, 0, 0)

#define BPW   4            // batches per group
#define ROWS  (BPW * 12)   // 48 joint-rows per group
#define XPAD  136          // row stride (bf16) for q/k/ctx: 272B, 16B-aligned
#define VPAD  20           // vT row stride: 40B -> bank coeff 10 (odd*2), 8B-aligned
#define PPAD  20           // P row stride
#define NGRP  4096         // total batch-groups (16384 / BPW)
#define GRID  768          // 3 WG/CU x 256 CU -- exact residency fill

struct SMem {
    u16   qs[ROWS * XPAD];       // q rows [48][128]; ctx overlays per-head
    u16   ks[ROWS * XPAD];       // k rows
    u16   vT[BPW * 128 * VPAD];  // per batch [feat][joint pad 20]; cols 12..19 zeroed once
    u16   P[4 * 16 * PPAD];      // per wave unnormalized exp [n][m pad 20]
    float bias_s[16 * 16];       // adj*scale*log2e; -1e30 for m>=12; 0 for n>=12
    float bvec[4 * 128];         // bq | bk | bv | bo
    float rls[4 * 16];           // per wave: 1/rowsum for each n
};                               // 52,480 B -> 3 WG/CU (limit 54,613)

__device__ __forceinline__ u16 f2b(float f) {   // fp32 -> bf16 RNE
    unsigned u = __builtin_bit_cast(unsigned, f);
    return (u16)((u + 0x7fffu + ((u >> 16) & 1u)) >> 16);
}

__device__ __forceinline__ void st4(u16* p, float a, float b, float c, float d) {
    ushort4 v; v.x = f2b(a); v.y = f2b(b); v.z = f2b(c); v.w = f2b(d);
    *(ushort4*)p = v;   // ds_write_b64
}

__device__ __forceinline__ bf16x8 pack8(float4 a, float4 b) {
    bf16x8 r;
    r[0] = (short)f2b(a.x); r[1] = (short)f2b(a.y);
    r[2] = (short)f2b(a.z); r[3] = (short)f2b(a.w);
    r[4] = (short)f2b(b.x); r[5] = (short)f2b(b.y);
    r[6] = (short)f2b(b.z); r[7] = (short)f2b(b.w);
    return r;
}

__global__ void prep_w(const float* __restrict__ Wq, const float* __restrict__ Wk,
                       const float* __restrict__ Wv, const float* __restrict__ Wo,
                       u16* __restrict__ wbf) {
    int i = blockIdx.x * 256 + threadIdx.x;     // 0..16383
    wbf[i]         = f2b(Wq[i]);
    wbf[16384 + i] = f2b(Wk[i]);
    wbf[32768 + i] = f2b(Wv[i]);
    wbf[49152 + i] = f2b(Wo[i]);
}

__global__ __launch_bounds__(256, 3) void cja_main(
    const float* __restrict__ x, const float* __restrict__ vis,
    const float* __restrict__ bq, const float* __restrict__ bk,
    const float* __restrict__ bv, const float* __restrict__ bo,
    const float* __restrict__ bias_scale, const float* __restrict__ adj,
    const u16* __restrict__ wbf, float* __restrict__ out)
{
    extern __shared__ char smraw[];
    SMem& sm = *(SMem*)smraw;

    const int tid  = threadIdx.x;
    const int wave = tid >> 6;
    const int lane = tid & 63;
    const int lq   = lane >> 4;      // quadrant 0..3
    const int lm   = lane & 15;      // 0..15

    // ---- cross-round x prefetch (two half-stages; static-indexed) ----------
    float4 xra[6][2];   // ks2 0..1 raw fragments (48 VGPRs while live)
    float4 xrb[6][2];   // ks2 2..3 raw fragments (48 VGPRs while live)
    bf16x8 xf[12];      // packed bf16 fragments  (48 VGPRs; dead during phase 2)

    auto issueA = [&](int grp) {
        const float* xw = x + (size_t)grp * (BPW * 12 * 128);
        #pragma unroll
        for (int ks2 = 0; ks2 < 2; ks2++)
            #pragma unroll
            for (int nt = 0; nt < 3; nt++) {
                const float* xp = xw + (nt * 16 + lm) * 128 + ks2 * 32 + lq * 8;
                xra[ks2 * 3 + nt][0] = *(const float4*)xp;
                xra[ks2 * 3 + nt][1] = *(const float4*)(xp + 4);
            }
    };
    auto issueB = [&](int grp) {
        const float* xw = x + (size_t)grp * (BPW * 12 * 128);
        #pragma unroll
        for (int ks2 = 2; ks2 < 4; ks2++)
            #pragma unroll
            for (int nt = 0; nt < 3; nt++) {
                const float* xp = xw + (nt * 16 + lm) * 128 + ks2 * 32 + lq * 8;
                xrb[(ks2 - 2) * 3 + nt][0] = *(const float4*)xp;
                xrb[(ks2 - 2) * 3 + nt][1] = *(const float4*)(xp + 4);
            }
    };
    auto packA = [&]() {
        #pragma unroll
        for (int i = 0; i < 6; i++) xf[i] = pack8(xra[i][0], xra[i][1]);
    };
    auto packB = [&]() {
        #pragma unroll
        for (int i = 0; i < 6; i++) xf[6 + i] = pack8(xrb[i][0], xrb[i][1]);
    };

    issueA(blockIdx.x);  // round-0 loads fly over the one-time prologue
    issueB(blockIdx.x);

    // ---------------- One-time prologue -------------------------------------
    for (int i = tid; i < BPW * 128; i += 256) {          // zero vT cols 12..19
        unsigned* d = (unsigned*)(sm.vT + i * VPAD + 12); // byte 40i+24: 8B-aligned
        d[0] = 0u; d[1] = 0u; d[2] = 0u; d[3] = 0u;       // scatter never touches these
    }
    const float L2E = 1.4426950408889634f;
    {
        float scale = bias_scale[0] * L2E;
        int n = tid >> 4, m = tid & 15;
        float bval;
        if (m >= 12)     bval = -1e30f;                   // key-pad mask (exp2 -> 0)
        else if (n < 12) bval = adj[n * 12 + m] * scale;
        else             bval = 0.0f;                     // row pad: keep finite
        sm.bias_s[tid] = bval;
        if (tid < 128) {
            sm.bvec[tid]       = bq[tid];
            sm.bvec[128 + tid] = bk[tid];
            sm.bvec[256 + tid] = bv[tid];
            sm.bvec[384 + tid] = bo[tid];
        }
    }
    packA(); packB();   // one-time exposed latency for round 0
    __syncthreads();

    // ---- round-invariant phase-2/3 addressing ------------------------------
    const int bl  = wave;
    const int nql = (lm < 12) ? lm : 11;                  // clamp: no OOB reads
    const u16* qrowp = sm.qs + (bl * 12 + nql) * XPAD;
    const u16* krowp = sm.ks + (bl * 12 + nql) * XPAD;
    u16*   Pw  = sm.P + wave * (16 * PPAD);
    float* rlw = sm.rls + wave * 16;
    const u16* vTb = sm.vT + bl * (128 * VPAD);
    const int mrow0 = wave * 32 + lm;                     // weight row (feature)
    const int mrow1 = mrow0 + 16;
    float bias_b[4];
    #pragma unroll
    for (int rr = 0; rr < 4; rr++) bias_b[rr] = sm.bias_s[(lq * 4 + rr) * 16 + lm];

    f32x4 oacc[2][3];   // deferred output (bias folded), stored next round
    int lastB0 = 0;

    #pragma unroll 1
    for (int grp = blockIdx.x; grp < NGRP; grp += GRID) {
        const int  b0      = grp * BPW;
        const bool hasNext = (grp + GRID) < NGRP;

        // ---- deferred store of previous round's output (drains by B1) ------
        if (grp != (int)blockIdx.x) {
            #pragma unroll
            for (int mi = 0; mi < 2; mi++) {
                const int e0 = (wave * 2 + mi) * 16 + lq * 4;
                #pragma unroll
                for (int nt = 0; nt < 3; nt++) {
                    const int n = nt * 16 + lm;
                    *(f32x4*)(out + ((size_t)(lastB0 * 12 + n) << 7) + e0) = oacc[mi][nt];
                }
            }
        }
        lastB0 = b0;

        // ---- visibility for this round: per-wave register load -------------
        float vism;
        {
            int   j  = (lm < 12) ? lm : 0;
            float vr = vis[(size_t)(b0 + bl) * 12 + j];
            vism = (lm < 12) ? 10.0f * L2E * (1.0f - vr) : 0.0f;
        }

        // ---------------- Phase 1: fused Q/K then V GEMMs (x from xf) -------
        {
            const u16* Wq_b = wbf;
            const u16* Wk_b = wbf + 16384;
            f32x4 accq[2][3], acck[2][3];
            #pragma unroll
            for (int i = 0; i < 2; i++)
                #pragma unroll
                for (int j = 0; j < 3; j++) { accq[i][j] = (f32x4){0,0,0,0}; acck[i][j] = (f32x4){0,0,0,0}; }
            #pragma unroll
            for (int ks2 = 0; ks2 < 4; ks2++) {
                const int koff = ks2 * 32 + lq * 8;
                bf16x8 wq0 = *(const bf16x8*)(Wq_b + mrow0 * 128 + koff);
                bf16x8 wq1 = *(const bf16x8*)(Wq_b + mrow1 * 128 + koff);
                bf16x8 wk0 = *(const bf16x8*)(Wk_b + mrow0 * 128 + koff);
                bf16x8 wk1 = *(const bf16x8*)(Wk_b + mrow1 * 128 + koff);
                #pragma unroll
                for (int nt = 0; nt < 3; nt++) {
                    accq[0][nt] = MFMA(wq0, xf[ks2*3+nt], accq[0][nt]);   // C[e,n] = Wq . x^T
                    accq[1][nt] = MFMA(wq1, xf[ks2*3+nt], accq[1][nt]);
                    acck[0][nt] = MFMA(wk0, xf[ks2*3+nt], acck[0][nt]);
                    acck[1][nt] = MFMA(wk1, xf[ks2*3+nt], acck[1][nt]);
                }
            }
            // epilogue Q/K: transposed store -> q,k row-major [joint-row][feat]
            #pragma unroll
            for (int mi = 0; mi < 2; mi++) {
                const int e0 = (wave * 2 + mi) * 16 + lq * 4;
                float bq0 = sm.bvec[e0], bq1 = sm.bvec[e0+1], bq2 = sm.bvec[e0+2], bq3 = sm.bvec[e0+3];
                float bk0 = sm.bvec[128+e0], bk1 = sm.bvec[128+e0+1], bk2 = sm.bvec[128+e0+2], bk3 = sm.bvec[128+e0+3];
                #pragma unroll
                for (int nt = 0; nt < 3; nt++) {
                    const int n = nt * 16 + lm;                   // joint-row 0..47
                    st4(sm.qs + n * XPAD + e0, accq[mi][nt][0]+bq0, accq[mi][nt][1]+bq1,
                                               accq[mi][nt][2]+bq2, accq[mi][nt][3]+bq3);
                    st4(sm.ks + n * XPAD + e0, acck[mi][nt][0]+bk0, acck[mi][nt][1]+bk1,
                                               acck[mi][nt][2]+bk2, acck[mi][nt][3]+bk3);
                }
            }
            // V pass
            const u16* Wv_b = wbf + 32768;
            f32x4 accv[3][2];
            #pragma unroll
            for (int i = 0; i < 3; i++)
                #pragma unroll
                for (int j = 0; j < 2; j++) accv[i][j] = (f32x4){0,0,0,0};
            #pragma unroll
            for (int ks2 = 0; ks2 < 4; ks2++) {
                const int koff = ks2 * 32 + lq * 8;
                bf16x8 wv0 = *(const bf16x8*)(Wv_b + mrow0 * 128 + koff);
                bf16x8 wv1 = *(const bf16x8*)(Wv_b + mrow1 * 128 + koff);
                #pragma unroll
                for (int nt = 0; nt < 3; nt++) {
                    accv[nt][0] = MFMA(xf[ks2*3+nt], wv0, accv[nt][0]);   // C[n,e] = x . Wv^T
                    accv[nt][1] = MFMA(xf[ks2*3+nt], wv1, accv[nt][1]);
                }
            }
            // epilogue V: scatter -> vT[batch][feat][joint], stride 20 (conflict-free)
            #pragma unroll
            for (int nt2 = 0; nt2 < 2; nt2++) {
                const int e = (wave * 2 + nt2) * 16 + lm;         // feature column
                const float bvv = sm.bvec[256 + e];
                #pragma unroll
                for (int mt = 0; mt < 3; mt++) {
                    #pragma unroll
                    for (int r = 0; r < 4; r++) {
                        int n = mt * 16 + lq * 4 + r;             // joint-row 0..47
                        int bb = n / 12, j = n - bb * 12;
                        sm.vT[bb * (128 * VPAD) + e * VPAD + j] = f2b(accv[mt][nt2][r] + bvv);
                    }
                }
            }
        }
        __syncthreads();   // B1

        // ---------------- Phase 2: attention (wave w owns batch w) ----------
        {
            // Prefetch next group's x NOW: old xf is dead (consumed by phase 1),
            // so peak = xra48+xrb48+phase2 working set ~ 131 VGPR < 168 cap.
            // Stage A waits via counted vmcnt at packA; stage B drains at B2's
            // mandatory vmcnt(0) -- both fully covered by phase-2 compute.
            if (hasNext) { issueA(grp + GRID); issueB(grp + GRID); }

            const float SC2 = 0.2550348606381560f;        // (1/sqrt(32))*log2(e)
            const bf16x8 z8 = {0,0,0,0,0,0,0,0};
            #pragma unroll
            for (int h = 0; h < 4; h++) {
                bf16x8 qa = *(const bf16x8*)(qrowp + h * 32 + lq * 8);
                bf16x8 kb = *(const bf16x8*)(krowp + h * 32 + lq * 8);
                f32x4 sc = MFMA(qa, kb, ((f32x4){0,0,0,0}));      // scores[n,m]
                #pragma unroll
                for (int r = 0; r < 4; r++) {
                    float s2 = sc[r] * SC2 + bias_b[r] - vism;    // base-2 domain
                    float e  = __builtin_amdgcn_exp2f(s2);        // 0 exactly for pads
                    float l  = e;
                    l += __shfl_xor(l, 1, 16);
                    l += __shfl_xor(l, 2, 16);
                    l += __shfl_xor(l, 4, 16);
                    l += __shfl_xor(l, 8, 16);
                    Pw[(lq * 4 + r) * PPAD + lm] = f2b(e);        // unnormalized
                    if (lm == 0) rlw[lq * 4 + r] = __builtin_amdgcn_rcpf(l);
                }
                float rln = rlw[lm];                              // 1/l for col n=lm
                bf16x8 pb = z8;                                   // quads 2,3 = zero (K-ext 16)
                if (lq < 2) {
                    const bf16x4* pp = (const bf16x4*)(Pw + lm * PPAD + lq * 8);
                    pb = __builtin_shufflevector(pp[0], pp[1], 0, 1, 2, 3, 4, 5, 6, 7);
                }
                #pragma unroll
                for (int mt = 0; mt < 2; mt++) {
                    bf16x8 va = z8;
                    if (lq < 2) {
                        const bf16x4* vp = (const bf16x4*)(vTb + (h * 32 + mt * 16 + lm) * VPAD + lq * 8);
                        va = __builtin_shufflevector(vp[0], vp[1], 0, 1, 2, 3, 4, 5, 6, 7);
                    }
                    f32x4 c = MFMA(va, pb, ((f32x4){0,0,0,0}));   // C[e',n]
                    if (lm < 12) {                                 // ctx overlays qs
                        u16* d = sm.qs + (bl * 12 + lm) * XPAD + h * 32 + mt * 16 + lq * 4;
                        st4(d, c[0] * rln, c[1] * rln, c[2] * rln, c[3] * rln);
                    }
                }
            }

            if (hasNext) packA();                 // counted vmcnt: B stays in flight
        }
        __syncthreads();   // B2 (vmcnt(0): stage-B arrivals complete here)

        // ---------------- Phase 3: output projection (no store yet) ---------
        {
            if (hasNext) packB();                 // pure VALU, data already drained

            const u16* Wo_b = wbf + 49152;
            f32x4 acc[2][3];
            #pragma unroll
            for (int i = 0; i < 2; i++)
                #pragma unroll
                for (int j = 0; j < 3; j++) acc[i][j] = (f32x4){0,0,0,0};
            #pragma unroll
            for (int ks2 = 0; ks2 < 4; ks2++) {
                const int koff = ks2 * 32 + lq * 8;
                bf16x8 a0 = *(const bf16x8*)(Wo_b + mrow0 * 128 + koff);
                bf16x8 a1 = *(const bf16x8*)(Wo_b + mrow1 * 128 + koff);
                #pragma unroll
                for (int nt = 0; nt < 3; nt++) {
                    bf16x8 bfr = *(const bf16x8*)(sm.qs + (nt * 16 + lm) * XPAD + koff);
                    acc[0][nt] = MFMA(a0, bfr, acc[0][nt]);
                    acc[1][nt] = MFMA(a1, bfr, acc[1][nt]);
                }
            }
            #pragma unroll
            for (int mi = 0; mi < 2; mi++) {
                const int e0 = (wave * 2 + mi) * 16 + lq * 4;
                float bo0 = sm.bvec[384+e0], bo1 = sm.bvec[384+e0+1],
                      bo2 = sm.bvec[384+e0+2], bo3 = sm.bvec[384+e0+3];
                #pragma unroll
                for (int nt = 0; nt < 3; nt++) {
                    oacc[mi][nt][0] = acc[mi][nt][0] + bo0;
                    oacc[mi][nt][1] = acc[mi][nt][1] + bo1;
                    oacc[mi][nt][2] = acc[mi][nt][2] + bo2;
                    oacc[mi][nt][3] = acc[mi][nt][3] + bo3;
                }
            }
        }
        if (hasNext) __syncthreads();   // B3: protect qs/ks/vT for next P1
    }

    // ---- final round's deferred store --------------------------------------
    #pragma unroll
    for (int mi = 0; mi < 2; mi++) {
        const int e0 = (wave * 2 + mi) * 16 + lq * 4;
        #pragma unroll
        for (int nt = 0; nt < 3; nt++) {
            const int n = nt * 16 + lm;
            *(f32x4*)(out + ((size_t)(lastB0 * 12 + n) << 7) + e0) = oacc[mi][nt];
        }
    }
}

extern "C" void kernel_launch(void* const* d_in, const int* in_sizes, int n_in,
                              void* d_out, int out_size, void* d_ws, size_t ws_size,
                              hipStream_t stream) {
    const float* x   = (const float*)d_in[0];
    const float* vis = (const float*)d_in[1];
    const float* Wq  = (const float*)d_in[2];
    const float* bq  = (const float*)d_in[3];
    const float* Wk  = (const float*)d_in[4];
    const float* bk  = (const float*)d_in[5];
    const float* Wv  = (const float*)d_in[6];
    const float* bv  = (const float*)d_in[7];
    const float* Wo  = (const float*)d_in[8];
    const float* bo  = (const float*)d_in[9];
    const float* bs  = (const float*)d_in[10];
    const float* adj = (const float*)d_in[11];
    u16* wbf = (u16*)d_ws;   // 4 x 128x128 bf16 = 128KB

    prep_w<<<64, 256, 0, stream>>>(Wq, Wk, Wv, Wo, wbf);
    cja_main<<<GRID, 256, sizeof(SMem), stream>>>(
        x, vis, bq, bk, bv, bo, bs, adj, wbf, (float*)d_out);
}

// Round 4
// 321.336 us; speedup vs baseline: 1.6609x; 1.3725x over previous
//
#include <hip/hip_runtime.h>

// CrossJointAttention fused kernel for MI355X (gfx950) -- Round 6.
// B=16384, N=12 joints, D=128, H=4, hd=32. fp32 in/out, bf16 MFMA internally.
//
// R6 vs R5 post-mortem (R5: 330us, VGPR stuck at 84, 376MB scratch writes =
// exactly the 384B fp32 prefetch stage; allocator either targets 6 waves/EU
// on its own or the unified VGPR+AGPR file leaves no headroom):
//  - x PRE-CONVERTED to bf16 once per launch (prep_x -> workspace). Phase 1
//    loads MFMA-ready bf16x8 fragments (12x dwordx4): no pack VALU at all,
//    half the x bytes. Guarded by ws_size check; compiled fallback path
//    (fp32 load+pack, no prefetch) if workspace is too small.
//  - Cross-round prefetch is now only xf[12] = 48 VGPRs (was 96 raw + 48),
//    issued at phase-2 start, drained by B2's mandatory vmcnt(0) -- covered
//    by attention compute.
//  - amdgpu_waves_per_eu(3,3): pins allocator budget to 168 VGPRs (LDS caps
//    at 3 WG/CU anyway, so max=3 loses nothing).
//  - Kept from R5: grid 768 persistent + grid-stride, one-time prologue,
//    per-wave vis register load, deferred output stores.
// Numerics (MFMA layouts, exp2 softmax, VPAD=20 vT, P round-trip, bf16 RNE)
// unchanged -> bit-identical output to R2/R5.

typedef unsigned short u16;
typedef short bf16x8 __attribute__((ext_vector_type(8)));   // 8 bf16 = 4 VGPRs
typedef short bf16x4 __attribute__((ext_vector_type(4)));   // 4 bf16 = 2 VGPRs
typedef float f32x4 __attribute__((ext_vector_type(4)));

#define MFMA(a, b, c) __builtin_amdgcn_mfma_f32_16x16x32_bf16((a), (b), (c), 0, 0, 0)

#define BPW   4            // batches per group
#define ROWS  (BPW * 12)   // 48 joint-rows per group
#define XPAD  136          // row stride (bf16) for q/k/ctx: 272B, 16B-aligned
#define VPAD  20           // vT row stride: 40B -> bank coeff 10 (odd*2), 8B-aligned
#define PPAD  20           // P row stride
#define NGRP  4096         // total batch-groups (16384 / BPW)
#define GRID  768          // 3 WG/CU x 256 CU -- exact residency fill

struct SMem {
    u16   qs[ROWS * XPAD];       // q rows [48][128]; ctx overlays per-head
    u16   ks[ROWS * XPAD];       // k rows
    u16   vT[BPW * 128 * VPAD];  // per batch [feat][joint pad 20]; cols 12..19 zeroed once
    u16   P[4 * 16 * PPAD];      // per wave unnormalized exp [n][m pad 20]
    float bias_s[16 * 16];       // adj*scale*log2e; -1e30 for m>=12; 0 for n>=12
    float bvec[4 * 128];         // bq | bk | bv | bo
    float rls[4 * 16];           // per wave: 1/rowsum for each n
};                               // 52,480 B -> 3 WG/CU (limit 54,613)

__device__ __forceinline__ u16 f2b(float f) {   // fp32 -> bf16 RNE
    unsigned u = __builtin_bit_cast(unsigned, f);
    return (u16)((u + 0x7fffu + ((u >> 16) & 1u)) >> 16);
}

__device__ __forceinline__ void st4(u16* p, float a, float b, float c, float d) {
    ushort4 v; v.x = f2b(a); v.y = f2b(b); v.z = f2b(c); v.w = f2b(d);
    *(ushort4*)p = v;   // ds_write_b64
}

__device__ __forceinline__ bf16x8 pack8(float4 a, float4 b) {
    bf16x8 r;
    r[0] = (short)f2b(a.x); r[1] = (short)f2b(a.y);
    r[2] = (short)f2b(a.z); r[3] = (short)f2b(a.w);
    r[4] = (short)f2b(b.x); r[5] = (short)f2b(b.y);
    r[6] = (short)f2b(b.z); r[7] = (short)f2b(b.w);
    return r;
}

__global__ void prep_w(const float* __restrict__ Wq, const float* __restrict__ Wk,
                       const float* __restrict__ Wv, const float* __restrict__ Wo,
                       u16* __restrict__ wbf) {
    int i = blockIdx.x * 256 + threadIdx.x;     // 0..16383
    wbf[i]         = f2b(Wq[i]);
    wbf[16384 + i] = f2b(Wk[i]);
    wbf[32768 + i] = f2b(Wv[i]);
    wbf[49152 + i] = f2b(Wo[i]);
}

__global__ void prep_x(const float* __restrict__ x, u16* __restrict__ xbf) {
    size_t i = ((size_t)blockIdx.x * 256 + threadIdx.x) * 8;   // 8 elems/thread
    float4 a = *(const float4*)(x + i);
    float4 b = *(const float4*)(x + i + 4);
    *(bf16x8*)(xbf + i) = pack8(a, b);          // same RNE as in-kernel pack
}

template <bool XBF>
__global__ __launch_bounds__(256) __attribute__((amdgpu_waves_per_eu(3, 3)))
void cja_main(
    const float* __restrict__ x, const u16* __restrict__ xbf,
    const float* __restrict__ vis,
    const float* __restrict__ bq, const float* __restrict__ bk,
    const float* __restrict__ bv, const float* __restrict__ bo,
    const float* __restrict__ bias_scale, const float* __restrict__ adj,
    const u16* __restrict__ wbf, float* __restrict__ out)
{
    extern __shared__ char smraw[];
    SMem& sm = *(SMem*)smraw;

    const int tid  = threadIdx.x;
    const int wave = tid >> 6;
    const int lane = tid & 63;
    const int lq   = lane >> 4;      // quadrant 0..3
    const int lm   = lane & 15;      // 0..15

    // ---- cross-round x fragments: MFMA-ready bf16, 48 VGPRs (XBF only) -----
    bf16x8 xf[12];
    auto loadxf = [&](int grp) {     // 12x global_load_dwordx4, no pack
        const u16* xw = xbf + (size_t)grp * (ROWS * 128);
        #pragma unroll
        for (int ks2 = 0; ks2 < 4; ks2++)
            #pragma unroll
            for (int nt = 0; nt < 3; nt++)
                xf[ks2 * 3 + nt] =
                    *(const bf16x8*)(xw + (nt * 16 + lm) * 128 + ks2 * 32 + lq * 8);
    };

    if constexpr (XBF) loadxf(blockIdx.x);   // round-0 loads fly over prologue

    // ---------------- One-time prologue -------------------------------------
    for (int i = tid; i < BPW * 128; i += 256) {          // zero vT cols 12..19
        unsigned* d = (unsigned*)(sm.vT + i * VPAD + 12); // byte 40i+24: 8B-aligned
        d[0] = 0u; d[1] = 0u; d[2] = 0u; d[3] = 0u;       // scatter never touches these
    }
    const float L2E = 1.4426950408889634f;
    {
        float scale = bias_scale[0] * L2E;
        int n = tid >> 4, m = tid & 15;
        float bval;
        if (m >= 12)     bval = -1e30f;                   // key-pad mask (exp2 -> 0)
        else if (n < 12) bval = adj[n * 12 + m] * scale;
        else             bval = 0.0f;                     // row pad: keep finite
        sm.bias_s[tid] = bval;
        if (tid < 128) {
            sm.bvec[tid]       = bq[tid];
            sm.bvec[128 + tid] = bk[tid];
            sm.bvec[256 + tid] = bv[tid];
            sm.bvec[384 + tid] = bo[tid];
        }
    }
    __syncthreads();

    // ---- round-invariant phase-2/3 addressing ------------------------------
    const int bl  = wave;
    const int nql = (lm < 12) ? lm : 11;                  // clamp: no OOB reads
    const u16* qrowp = sm.qs + (bl * 12 + nql) * XPAD;
    const u16* krowp = sm.ks + (bl * 12 + nql) * XPAD;
    u16*   Pw  = sm.P + wave * (16 * PPAD);
    float* rlw = sm.rls + wave * 16;
    const u16* vTb = sm.vT + bl * (128 * VPAD);
    const int mrow0 = wave * 32 + lm;                     // weight row (feature)
    const int mrow1 = mrow0 + 16;
    float bias_b[4];
    #pragma unroll
    for (int rr = 0; rr < 4; rr++) bias_b[rr] = sm.bias_s[(lq * 4 + rr) * 16 + lm];

    // ---- shared epilogue helpers (identical math both paths) ---------------
    auto epiQK = [&](f32x4 (&accq)[2][3], f32x4 (&acck)[2][3]) {
        #pragma unroll
        for (int mi = 0; mi < 2; mi++) {
            const int e0 = (wave * 2 + mi) * 16 + lq * 4;
            float bq0 = sm.bvec[e0], bq1 = sm.bvec[e0+1], bq2 = sm.bvec[e0+2], bq3 = sm.bvec[e0+3];
            float bk0 = sm.bvec[128+e0], bk1 = sm.bvec[128+e0+1], bk2 = sm.bvec[128+e0+2], bk3 = sm.bvec[128+e0+3];
            #pragma unroll
            for (int nt = 0; nt < 3; nt++) {
                const int n = nt * 16 + lm;                   // joint-row 0..47
                st4(sm.qs + n * XPAD + e0, accq[mi][nt][0]+bq0, accq[mi][nt][1]+bq1,
                                           accq[mi][nt][2]+bq2, accq[mi][nt][3]+bq3);
                st4(sm.ks + n * XPAD + e0, acck[mi][nt][0]+bk0, acck[mi][nt][1]+bk1,
                                           acck[mi][nt][2]+bk2, acck[mi][nt][3]+bk3);
            }
        }
    };
    auto epiV = [&](f32x4 (&accv)[3][2]) {
        #pragma unroll
        for (int nt2 = 0; nt2 < 2; nt2++) {
            const int e = (wave * 2 + nt2) * 16 + lm;         // feature column
            const float bvv = sm.bvec[256 + e];
            #pragma unroll
            for (int mt = 0; mt < 3; mt++) {
                #pragma unroll
                for (int r = 0; r < 4; r++) {
                    int n = mt * 16 + lq * 4 + r;             // joint-row 0..47
                    int bb = n / 12, j = n - bb * 12;
                    sm.vT[bb * (128 * VPAD) + e * VPAD + j] = f2b(accv[mt][nt2][r] + bvv);
                }
            }
        }
    };

    f32x4 oacc[2][3];   // deferred output (bias folded), stored next round
    int lastB0 = 0;

    #pragma unroll 1
    for (int grp = blockIdx.x; grp < NGRP; grp += GRID) {
        const int  b0      = grp * BPW;
        const bool hasNext = (grp + GRID) < NGRP;

        // ---- deferred store of previous round's output (drains by B1) ------
        if (grp != (int)blockIdx.x) {
            #pragma unroll
            for (int mi = 0; mi < 2; mi++) {
                const int e0 = (wave * 2 + mi) * 16 + lq * 4;
                #pragma unroll
                for (int nt = 0; nt < 3; nt++) {
                    const int n = nt * 16 + lm;
                    *(f32x4*)(out + ((size_t)(lastB0 * 12 + n) << 7) + e0) = oacc[mi][nt];
                }
            }
        }
        lastB0 = b0;

        // ---- visibility for this round: per-wave register load -------------
        float vism;
        {
            int   j  = (lm < 12) ? lm : 0;
            float vr = vis[(size_t)(b0 + bl) * 12 + j];
            vism = (lm < 12) ? 10.0f * L2E * (1.0f - vr) : 0.0f;
        }

        // ---------------- Phase 1: fused Q/K/V GEMMs ------------------------
        if constexpr (XBF) {
            // QK pass (xf[12] already resident; 48 acc regs live)
            const u16* Wq_b = wbf;
            const u16* Wk_b = wbf + 16384;
            f32x4 accq[2][3], acck[2][3];
            #pragma unroll
            for (int i = 0; i < 2; i++)
                #pragma unroll
                for (int j = 0; j < 3; j++) { accq[i][j] = (f32x4){0,0,0,0}; acck[i][j] = (f32x4){0,0,0,0}; }
            #pragma unroll
            for (int ks2 = 0; ks2 < 4; ks2++) {
                const int koff = ks2 * 32 + lq * 8;
                bf16x8 wq0 = *(const bf16x8*)(Wq_b + mrow0 * 128 + koff);
                bf16x8 wq1 = *(const bf16x8*)(Wq_b + mrow1 * 128 + koff);
                bf16x8 wk0 = *(const bf16x8*)(Wk_b + mrow0 * 128 + koff);
                bf16x8 wk1 = *(const bf16x8*)(Wk_b + mrow1 * 128 + koff);
                #pragma unroll
                for (int nt = 0; nt < 3; nt++) {
                    accq[0][nt] = MFMA(wq0, xf[ks2*3+nt], accq[0][nt]);   // C[e,n] = Wq . x^T
                    accq[1][nt] = MFMA(wq1, xf[ks2*3+nt], accq[1][nt]);
                    acck[0][nt] = MFMA(wk0, xf[ks2*3+nt], acck[0][nt]);
                    acck[1][nt] = MFMA(wk1, xf[ks2*3+nt], acck[1][nt]);
                }
            }
            epiQK(accq, acck);
            // V pass
            const u16* Wv_b = wbf + 32768;
            f32x4 accv[3][2];
            #pragma unroll
            for (int i = 0; i < 3; i++)
                #pragma unroll
                for (int j = 0; j < 2; j++) accv[i][j] = (f32x4){0,0,0,0};
            #pragma unroll
            for (int ks2 = 0; ks2 < 4; ks2++) {
                const int koff = ks2 * 32 + lq * 8;
                bf16x8 wv0 = *(const bf16x8*)(Wv_b + mrow0 * 128 + koff);
                bf16x8 wv1 = *(const bf16x8*)(Wv_b + mrow1 * 128 + koff);
                #pragma unroll
                for (int nt = 0; nt < 3; nt++) {
                    accv[nt][0] = MFMA(xf[ks2*3+nt], wv0, accv[nt][0]);   // C[n,e] = x . Wv^T
                    accv[nt][1] = MFMA(xf[ks2*3+nt], wv1, accv[nt][1]);
                }
            }
            epiV(accv);
        } else {
            // Fallback: fp32 x load + pack per K-chunk (R2-proven pressure)
            const u16* Wq_b = wbf;
            const u16* Wk_b = wbf + 16384;
            const u16* Wv_b = wbf + 32768;
            const float* xw = x + (size_t)b0 * 1536;   // 12*128 per batch
            f32x4 accq[2][3], acck[2][3], accv[3][2];
            #pragma unroll
            for (int i = 0; i < 2; i++)
                #pragma unroll
                for (int j = 0; j < 3; j++) { accq[i][j] = (f32x4){0,0,0,0}; acck[i][j] = (f32x4){0,0,0,0}; }
            #pragma unroll
            for (int i = 0; i < 3; i++)
                #pragma unroll
                for (int j = 0; j < 2; j++) accv[i][j] = (f32x4){0,0,0,0};
            #pragma unroll
            for (int ks2 = 0; ks2 < 4; ks2++) {
                const int koff = ks2 * 32 + lq * 8;
                bf16x8 xt[3];
                #pragma unroll
                for (int nt = 0; nt < 3; nt++) {
                    const float* xp = xw + (nt * 16 + lm) * 128 + koff;
                    float4 u0 = *(const float4*)xp;
                    float4 u1 = *(const float4*)(xp + 4);
                    xt[nt] = pack8(u0, u1);
                }
                bf16x8 wq0 = *(const bf16x8*)(Wq_b + mrow0 * 128 + koff);
                bf16x8 wq1 = *(const bf16x8*)(Wq_b + mrow1 * 128 + koff);
                bf16x8 wk0 = *(const bf16x8*)(Wk_b + mrow0 * 128 + koff);
                bf16x8 wk1 = *(const bf16x8*)(Wk_b + mrow1 * 128 + koff);
                bf16x8 wv0 = *(const bf16x8*)(Wv_b + mrow0 * 128 + koff);
                bf16x8 wv1 = *(const bf16x8*)(Wv_b + mrow1 * 128 + koff);
                #pragma unroll
                for (int nt = 0; nt < 3; nt++) {
                    accq[0][nt] = MFMA(wq0, xt[nt], accq[0][nt]);
                    accq[1][nt] = MFMA(wq1, xt[nt], accq[1][nt]);
                    acck[0][nt] = MFMA(wk0, xt[nt], acck[0][nt]);
                    acck[1][nt] = MFMA(wk1, xt[nt], acck[1][nt]);
                    accv[nt][0] = MFMA(xt[nt], wv0, accv[nt][0]);
                    accv[nt][1] = MFMA(xt[nt], wv1, accv[nt][1]);
                }
            }
            epiQK(accq, acck);
            epiV(accv);
        }
        __syncthreads();   // B1

        // ---------------- Phase 2: attention (wave w owns batch w) ----------
        {
            // Prefetch next round's x fragments NOW (old xf dead after P1).
            // Drained at latest by B2's mandatory vmcnt(0) -- covered by the
            // attention compute below.
            if constexpr (XBF) { if (hasNext) loadxf(grp + GRID); }

            const float SC2 = 0.2550348606381560f;        // (1/sqrt(32))*log2(e)
            const bf16x8 z8 = {0,0,0,0,0,0,0,0};
            #pragma unroll
            for (int h = 0; h < 4; h++) {
                bf16x8 qa = *(const bf16x8*)(qrowp + h * 32 + lq * 8);
                bf16x8 kb = *(const bf16x8*)(krowp + h * 32 + lq * 8);
                f32x4 sc = MFMA(qa, kb, ((f32x4){0,0,0,0}));      // scores[n,m]
                #pragma unroll
                for (int r = 0; r < 4; r++) {
                    float s2 = sc[r] * SC2 + bias_b[r] - vism;    // base-2 domain
                    float e  = __builtin_amdgcn_exp2f(s2);        // 0 exactly for pads
                    float l  = e;
                    l += __shfl_xor(l, 1, 16);
                    l += __shfl_xor(l, 2, 16);
                    l += __shfl_xor(l, 4, 16);
                    l += __shfl_xor(l, 8, 16);
                    Pw[(lq * 4 + r) * PPAD + lm] = f2b(e);        // unnormalized
                    if (lm == 0) rlw[lq * 4 + r] = __builtin_amdgcn_rcpf(l);
                }
                float rln = rlw[lm];                              // 1/l for col n=lm
                bf16x8 pb = z8;                                   // quads 2,3 = zero (K-ext 16)
                if (lq < 2) {
                    const bf16x4* pp = (const bf16x4*)(Pw + lm * PPAD + lq * 8);
                    pb = __builtin_shufflevector(pp[0], pp[1], 0, 1, 2, 3, 4, 5, 6, 7);
                }
                #pragma unroll
                for (int mt = 0; mt < 2; mt++) {
                    bf16x8 va = z8;
                    if (lq < 2) {
                        const bf16x4* vp = (const bf16x4*)(vTb + (h * 32 + mt * 16 + lm) * VPAD + lq * 8);
                        va = __builtin_shufflevector(vp[0], vp[1], 0, 1, 2, 3, 4, 5, 6, 7);
                    }
                    f32x4 c = MFMA(va, pb, ((f32x4){0,0,0,0}));   // C[e',n]
                    if (lm < 12) {                                 // ctx overlays qs
                        u16* d = sm.qs + (bl * 12 + lm) * XPAD + h * 32 + mt * 16 + lq * 4;
                        st4(d, c[0] * rln, c[1] * rln, c[2] * rln, c[3] * rln);
                    }
                }
            }
        }
        __syncthreads();   // B2 (vmcnt(0): prefetch arrivals complete here)

        // ---------------- Phase 3: output projection (no store yet) ---------
        {
            const u16* Wo_b = wbf + 49152;
            f32x4 acc[2][3];
            #pragma unroll
            for (int i = 0; i < 2; i++)
                #pragma unroll
                for (int j = 0; j < 3; j++) acc[i][j] = (f32x4){0,0,0,0};
            #pragma unroll
            for (int ks2 = 0; ks2 < 4; ks2++) {
                const int koff = ks2 * 32 + lq * 8;
                bf16x8 a0 = *(const bf16x8*)(Wo_b + mrow0 * 128 + koff);
                bf16x8 a1 = *(const bf16x8*)(Wo_b + mrow1 * 128 + koff);
                #pragma unroll
                for (int nt = 0; nt < 3; nt++) {
                    bf16x8 bfr = *(const bf16x8*)(sm.qs + (nt * 16 + lm) * XPAD + koff);
                    acc[0][nt] = MFMA(a0, bfr, acc[0][nt]);
                    acc[1][nt] = MFMA(a1, bfr, acc[1][nt]);
                }
            }
            #pragma unroll
            for (int mi = 0; mi < 2; mi++) {
                const int e0 = (wave * 2 + mi) * 16 + lq * 4;
                float bo0 = sm.bvec[384+e0], bo1 = sm.bvec[384+e0+1],
                      bo2 = sm.bvec[384+e0+2], bo3 = sm.bvec[384+e0+3];
                #pragma unroll
                for (int nt = 0; nt < 3; nt++) {
                    oacc[mi][nt][0] = acc[mi][nt][0] + bo0;
                    oacc[mi][nt][1] = acc[mi][nt][1] + bo1;
                    oacc[mi][nt][2] = acc[mi][nt][2] + bo2;
                    oacc[mi][nt][3] = acc[mi][nt][3] + bo3;
                }
            }
        }
        if (hasNext) __syncthreads();   // B3: protect qs/ks/vT for next P1
    }

    // ---- final round's deferred store --------------------------------------
    #pragma unroll
    for (int mi = 0; mi < 2; mi++) {
        const int e0 = (wave * 2 + mi) * 16 + lq * 4;
        #pragma unroll
        for (int nt = 0; nt < 3; nt++) {
            const int n = nt * 16 + lm;
            *(f32x4*)(out + ((size_t)(lastB0 * 12 + n) << 7) + e0) = oacc[mi][nt];
        }
    }
}

extern "C" void kernel_launch(void* const* d_in, const int* in_sizes, int n_in,
                              void* d_out, int out_size, void* d_ws, size_t ws_size,
                              hipStream_t stream) {
    const float* x   = (const float*)d_in[0];
    const float* vis = (const float*)d_in[1];
    const float* Wq  = (const float*)d_in[2];
    const float* bq  = (const float*)d_in[3];
    const float* Wk  = (const float*)d_in[4];
    const float* bk  = (const float*)d_in[5];
    const float* Wv  = (const float*)d_in[6];
    const float* bv  = (const float*)d_in[7];
    const float* Wo  = (const float*)d_in[8];
    const float* bo  = (const float*)d_in[9];
    const float* bs  = (const float*)d_in[10];
    const float* adj = (const float*)d_in[11];
    u16* wbf = (u16*)d_ws;               // 4 x 128x128 bf16 = 128 KB
    u16* xbf = wbf + 65536;              // 16384*12*128 bf16 = 48 MB

    const size_t need = 131072 + (size_t)16384 * 12 * 128 * 2;

    prep_w<<<64, 256, 0, stream>>>(Wq, Wk, Wv, Wo, wbf);
    if (ws_size >= need) {
        prep_x<<<12288, 256, 0, stream>>>(x, xbf);
        cja_main<true><<<GRID, 256, sizeof(SMem), stream>>>(
            x, xbf, vis, bq, bk, bv, bo, bs, adj, wbf, (float*)d_out);
    } else {
        cja_main<false><<<GRID, 256, sizeof(SMem), stream>>>(
            x, xbf, vis, bq, bk, bv, bo, bs, adj, wbf, (float*)d_out);
    }
}